// Round 1
// 607.771 us; speedup vs baseline: 1.0240x; 1.0240x over previous
//
#include <hip/hip_runtime.h>
#include <hip/hip_bf16.h>

// GCN 4-layer, linear network => collapse to:
// out = A^4 x0 * c4 + A^3 1 * c3 + A^2 1 * c2 + A 1 * c1 + b4,
// A = D^-1/2 (Adj+I) D^-1/2. Propagate in scaled space u' = D^-1 (Adj+I) u,
// epilogue multiplies sqrt(deg). Channels (x-path, ones-path) packed float2.
// Dtypes (R1-R4 verified): read_length int32, edge_index int32, W/b fp32, out fp32.
//
// R8: coarsen radix buckets BSH 8->10 (NB 2048->512, 1024 nodes/bucket).
// R7 counters: scatter = 162us with WRITE_SIZE 218MB vs 32MB logical (7x
// amplification). Cause: 1M runs of ~30B, per-block partial-line frontier =
// NB lines = 128KB * 2 blk/CU * 32 CU = 8MB/XCD > 4MB L2 -> partial-line
// evictions + DRAM RMW. With NB=512: 262K runs of ~122B (lines mostly
// single-run -> written once, full), frontier 32KB/block = 2MB/XCD < L2.
// csr_build scales to 1024-node buckets: 1024 threads, 1 node/thread,
// pack = 10-bit local dst + 19-bit src. Gather sweeps unchanged.

#define BLK  256
#define SBLK 1024         // scatter/count block (occupancy fix)
#define NB   512          // buckets (R8: was 2048)
#define BSH  10           // bucket = dst >> 10  (1024 nodes / bucket)
#define PB   512          // partition blocks

// If rl were int64 (values in [0,20000)), every odd int32 word is 0.
__global__ void probe_i64(const int* __restrict__ rl32, int* __restrict__ flag) {
    int acc = 0;
    for (int k = threadIdx.x; k < 1024; k += blockDim.x)
        acc |= rl32[2 * k + 1];
    if (acc != 0) atomicOr(flag, 1);   // 1 => int32 layout
}

__global__ __launch_bounds__(SBLK)
void bucket_count(const int* __restrict__ dst, int* __restrict__ table, int E) {
    __shared__ int h[NB];
    int j = blockIdx.x, t = threadIdx.x;
    for (int b = t; b < NB; b += SBLK) h[b] = 0;
    __syncthreads();
    int chunk = (E + PB - 1) / PB;
    int beg = j * chunk, end = min(beg + chunk, E);
    for (int e = beg + t; e < end; e += SBLK)
        atomicAdd(&h[((unsigned)dst[e]) >> BSH], 1);
    __syncthreads();
    for (int b = t; b < NB; b += SBLK) table[j * NB + b] = h[b];   // coalesced
}

__global__ void bucket_tot(const int* __restrict__ table, int* __restrict__ tot) {
    int b = blockIdx.x * blockDim.x + threadIdx.x;   // NB threads
    int s = 0;
    for (int j = 0; j < PB; ++j) s += table[j * NB + b];  // coalesced rows
    tot[b] = s;
}

__global__ void scan_base(const int* __restrict__ tot, int* __restrict__ base) {
    __shared__ int sm[BLK];
    int t = threadIdx.x;
    int loc[NB / BLK]; int s = 0;
#pragma unroll
    for (int k = 0; k < NB / BLK; ++k) { loc[k] = tot[t * (NB / BLK) + k]; s += loc[k]; }
    sm[t] = s; __syncthreads();
    int v = s;
    for (int off = 1; off < BLK; off <<= 1) {
        int add = (t >= off) ? sm[t - off] : 0;
        __syncthreads(); sm[t] += add; __syncthreads();
    }
    int run = sm[t] - v;   // exclusive across threads
#pragma unroll
    for (int k = 0; k < NB / BLK; ++k) { base[t * (NB / BLK) + k] = run; run += loc[k]; }
    if (t == BLK - 1) base[NB] = run;   // == E
}

// in-place: table[j][b] := bucket_base[b] + sum_{j'<j} table[j'][b]
__global__ void scan_table(int* __restrict__ table, const int* __restrict__ base) {
    int b = blockIdx.x * blockDim.x + threadIdx.x;
    int run = base[b];
    for (int j = 0; j < PB; ++j) {       // coalesced read+write per j
        int v = table[j * NB + b];
        table[j * NB + b] = run;
        run += v;
    }
}

__global__ __launch_bounds__(SBLK)
void scatter(const int* __restrict__ src, const int* __restrict__ dst,
             const int* __restrict__ table, unsigned* __restrict__ epart, int E) {
    __shared__ int cur[NB];
    int j = blockIdx.x, t = threadIdx.x;
    for (int b = t; b < NB; b += SBLK) cur[b] = table[j * NB + b];
    __syncthreads();
    int chunk = (E + PB - 1) / PB;
    int beg = j * chunk, end = min(beg + chunk, E);
    for (int e = beg + t; e < end; e += SBLK) {
        unsigned d = (unsigned)dst[e];
        int slot = atomicAdd(&cur[d >> BSH], 1);          // LDS cursor
        epart[slot] = ((d & 1023u) << 19) | (unsigned)src[e];
    }
}

// one-time: within each bucket, order edges by local dst node (CSR) and emit
// rowp[node]. 1024 nodes/bucket, one node per thread. Writes land in a
// 64KB block-local region (L2-merged).
__global__ __launch_bounds__(1024)
void csr_build(const unsigned* __restrict__ epart, const int* __restrict__ base,
               unsigned* __restrict__ epart2, int* __restrict__ rowp) {
    __shared__ int cnt[1024];
    __shared__ int sc[1024];
    __shared__ int cur[1024];
    int b = blockIdx.x, t = threadIdx.x;
    cnt[t] = 0;
    __syncthreads();
    int beg = base[b], end = base[b + 1];
    for (int e = beg + t; e < end; e += 1024)
        atomicAdd(&cnt[epart[e] >> 19], 1);
    __syncthreads();
    int v = cnt[t];
    sc[t] = v; __syncthreads();
    for (int off = 1; off < 1024; off <<= 1) {
        int add = (t >= off) ? sc[t - off] : 0;
        __syncthreads(); sc[t] += add; __syncthreads();
    }
    int start = beg + sc[t] - v;       // exclusive, global slot
    rowp[b * 1024 + t] = start;
    if (t == 1023) rowp[b * 1024 + 1024] = end;   // dup of next block's t=0 (same value)
    cur[t] = start;
    __syncthreads();
    for (int e = beg + t; e < end; e += 1024) {
        unsigned p = epart[e];
        int slot = atomicAdd(&cur[p >> 19], 1);
        epart2[slot] = p & 0x7FFFFu;   // just src (19 bits)
    }
}

// node init; in-degree free from rowp
__global__ void init_nodes(const int* __restrict__ rl, const int* __restrict__ rowp,
                           float* __restrict__ dinv, float2* __restrict__ v0,
                           const int* __restrict__ flag, int N) {
    int i = blockIdx.x * blockDim.x + threadIdx.x;
    if (i < N) {
        int v = (*flag) ? rl[i] : rl[2 * i];
        float d = (float)(rowp[i + 1] - rowp[i]) + 1.0f;   // + self-loop
        dinv[i] = 1.0f / d;
        float rs = rsqrtf(d);
        float2 u; u.x = rs * ((float)v * (1.0f / 20000.0f)); u.y = rs;
        v0[i] = u;
    }
}

__global__ void coeffs(const float* __restrict__ W1, const float* __restrict__ b1,
                       const float* __restrict__ W2, const float* __restrict__ b2,
                       const float* __restrict__ W3, const float* __restrict__ b3,
                       const float* __restrict__ W4, const float* __restrict__ b4,
                       float* __restrict__ c) {
    __shared__ float p3[16], q3[16], r3[16];
    int t = threadIdx.x;
    if (t == 0) {
        float p2[8], q2[8];
        for (int j = 0; j < 8; ++j) {
            float s1 = 0.f, s2 = 0.f;
            for (int k = 0; k < 4; ++k) {
                float w = W2[k * 8 + j];
                s1 += W1[k] * w;
                s2 += b1[k] * w;
            }
            p2[j] = s1; q2[j] = s2;
        }
        for (int m = 0; m < 16; ++m) {
            float s1 = 0.f, s2 = 0.f, s3 = 0.f;
            for (int j = 0; j < 8; ++j) {
                float w = W3[j * 16 + m];
                s1 += p2[j] * w; s2 += q2[j] * w;
                s3 += b2[j] * w;
            }
            p3[m] = s1; q3[m] = s2; r3[m] = s3;
        }
    }
    __syncthreads();
    if (t < 32) {
        float c4 = 0.f, c3 = 0.f, c2 = 0.f, c1 = 0.f;
        for (int k = 0; k < 16; ++k) {
            float w = W4[k * 32 + t];
            c4 += p3[k] * w; c3 += q3[k] * w; c2 += r3[k] * w;
            c1 += b3[k] * w;
        }
        c[t] = c4; c[32 + t] = c3; c[64 + t] = c2; c[96 + t] = c1;
    }
}

// one sweep: 4 lanes/node, register accumulate, x2 unrolled paired loads (MLP)
__global__ void gather_csr(const unsigned* __restrict__ epart2, const int* __restrict__ rowp,
                           const float2* __restrict__ vin, float2* __restrict__ vout,
                           const float* __restrict__ dinv, float* __restrict__ zsave, int N) {
    int t = blockIdx.x * blockDim.x + threadIdx.x;
    int i = t >> 2, l = t & 3;
    if (i >= N) return;
    int beg = rowp[i], end = rowp[i + 1];
    float a = 0.f, b = 0.f;
    int j = beg + l;
    for (; j + 4 < end; j += 8) {          // two independent loads in flight
        int s0 = epart2[j];
        int s1 = epart2[j + 4];
        float2 u0 = vin[s0];
        float2 u1 = vin[s1];
        a += u0.x + u1.x; b += u0.y + u1.y;
    }
    if (j < end) {
        float2 u = vin[epart2[j]];
        a += u.x; b += u.y;
    }
    a += __shfl_xor(a, 1); b += __shfl_xor(b, 1);
    a += __shfl_xor(a, 2); b += __shfl_xor(b, 2);
    if (l == 0) {
        float2 self = vin[i];
        float di = dinv[i];
        float2 o; o.x = (a + self.x) * di; o.y = (b + self.y) * di;
        vout[i] = o;
        if (zsave) zsave[i] = o.y;
    }
}

__global__ void write_out(const float2* __restrict__ v0, const float* __restrict__ z1,
                          const float* __restrict__ z2, const float* __restrict__ z3,
                          const float* __restrict__ dinv, const float* __restrict__ c,
                          const float* __restrict__ b4,
                          float* __restrict__ out, int N) {
    int t = blockIdx.x * blockDim.x + threadIdx.x;
    int i = t >> 5, f = t & 31;
    if (i < N) {
        float sq = rsqrtf(dinv[i]);  // = sqrt(deg)
        float v = sq * (v0[i].x * c[f] + z3[i] * c[32 + f] + z2[i] * c[64 + f]
                        + z1[i] * c[96 + f])
                  + b4[f];
        out[(size_t)i * 32 + f] = v;
    }
}

extern "C" void kernel_launch(void* const* d_in, const int* in_sizes, int n_in,
                              void* d_out, int out_size, void* d_ws, size_t ws_size,
                              hipStream_t stream) {
    const int N = in_sizes[0];
    const int E = in_sizes[1] / 2;
    const int* rl  = (const int*)d_in[0];
    const int* src = (const int*)d_in[1];
    const int* dst = src + E;
    const float* W1 = (const float*)d_in[2];
    const float* b1 = (const float*)d_in[3];
    const float* W2 = (const float*)d_in[4];
    const float* b2 = (const float*)d_in[5];
    const float* W3 = (const float*)d_in[6];
    const float* b3 = (const float*)d_in[7];
    const float* W4 = (const float*)d_in[8];
    const float* b4 = (const float*)d_in[9];

    const int gbNode = (N + 1023) / 1024;     // buckets containing nodes (489)
    const int rowpN  = gbNode * 1024 + 1;     // rowp entries

    // workspace (~19.1 MB)
    float*  dinv = (float*)d_ws;              // N
    float2* v0   = (float2*)(dinv + N);       // 2N floats
    float2* v1   = v0 + N;                    // 2N floats
    float*  z1   = (float*)(v1 + N);          // N
    float*  z2   = z1 + N;                    // N
    float*  z3   = z2 + N;                    // N
    int*    table = (int*)(z3 + N);           // PB*NB ints (1 MB)
    int*    rowp  = table + PB * NB;          // rowpN ints (~2 MB)
    int*    btot  = rowp + rowpN + 3;         // NB
    int*    bbase = btot + NB;                // NB+1
    float*  c     = (float*)(bbase + NB + 1); // 128
    int*    flag  = (int*)(c + 128);          // 1

    // packed edge arrays live in d_out (scratch until write_out)
    unsigned* epart  = (unsigned*)d_out;      // E uint32 (first 32 MB)
    unsigned* epart2 = epart + E;             // E uint32 (second 32 MB)

    hipMemsetAsync(flag, 0, sizeof(int), stream);
    probe_i64<<<1, BLK, 0, stream>>>(rl, flag);

    // radix partition by dst bucket — zero global atomics
    bucket_count<<<PB, SBLK, 0, stream>>>(dst, table, E);
    bucket_tot<<<NB / BLK, BLK, 0, stream>>>(table, btot);
    scan_base<<<1, BLK, 0, stream>>>(btot, bbase);
    scan_table<<<NB / BLK, BLK, 0, stream>>>(table, bbase);
    scatter<<<PB, SBLK, 0, stream>>>(src, dst, table, epart, E);

    // within-bucket CSR
    csr_build<<<gbNode, 1024, 0, stream>>>(epart, bbase, epart2, rowp);

    init_nodes<<<(N + BLK - 1) / BLK, BLK, 0, stream>>>(rl, rowp, dinv, v0, flag, N);
    coeffs<<<1, 64, 0, stream>>>(W1, b1, W2, b2, W3, b3, W4, b4, c);

    // 4 propagation sweeps, ping-pong v0<->v1
    const int gbG = (4 * N + BLK - 1) / BLK;
    gather_csr<<<gbG, BLK, 0, stream>>>(epart2, rowp, v0, v1, dinv, z1, N);
    gather_csr<<<gbG, BLK, 0, stream>>>(epart2, rowp, v1, v0, dinv, z2, N);
    gather_csr<<<gbG, BLK, 0, stream>>>(epart2, rowp, v0, v1, dinv, z3, N);
    gather_csr<<<gbG, BLK, 0, stream>>>(epart2, rowp, v1, v0, dinv, (float*)nullptr, N);

    write_out<<<(N * 32 + BLK - 1) / BLK, BLK, 0, stream>>>(
        v0, z1, z2, z3, dinv, c, b4, (float*)d_out, N);
}

// Round 2
// 517.510 us; speedup vs baseline: 1.2027x; 1.1744x over previous
//
#include <hip/hip_runtime.h>
#include <hip/hip_bf16.h>

// GCN 4-layer, linear network => collapse to:
// out = A^4 x0 * c4 + A^3 1 * c3 + A^2 1 * c2 + A 1 * c1 + b4,
// A = D^-1/2 (Adj+I) D^-1/2. Propagate in scaled space u' = D^-1 (Adj+I) u,
// epilogue multiplies sqrt(deg). Channels (x-path, ones-path) packed float2.
// Dtypes (R1-R4 verified): read_length int32, edge_index int32, W/b fp32, out fp32.
//
// R9: (a) scatter rewritten as block-local LDS counting sort. R8 counters:
// WRITE_SIZE still 155MB vs 32MB logical at only 1.5TB/s (19% peak) -> not
// BW-bound; partially-filled frontier lines are thrashed out of L2 by the
// streaming src/dst reads no matter how small the frontier. Fix: sort the
// 15.6K-edge chunk in LDS (count -> scan -> fill, 62KB buffer), then emit
// each bucket run with sequential coalesced full-line stores. Global lines
// written once, dense. (b) gather 4->8 lanes/node: dependent chain
// rowp->idx->value with avg 4 edges/lane leaves a serial tail; 8 lanes/node
// = ~2 edges/lane = one fully-parallel load round + 2x concurrent chains.

#define BLK  256
#define SBLK 1024         // scatter/count block
#define NB   512          // buckets
#define BSH  10           // bucket = dst >> 10  (1024 nodes / bucket)
#define PB   512          // partition blocks
#define BUFCAP 15872      // LDS sort buffer (chunk = ceil(8M/512) = 15625)

// If rl were int64 (values in [0,20000)), every odd int32 word is 0.
__global__ void probe_i64(const int* __restrict__ rl32, int* __restrict__ flag) {
    int acc = 0;
    for (int k = threadIdx.x; k < 1024; k += blockDim.x)
        acc |= rl32[2 * k + 1];
    if (acc != 0) atomicOr(flag, 1);   // 1 => int32 layout
}

__global__ __launch_bounds__(SBLK)
void bucket_count(const int* __restrict__ dst, int* __restrict__ table, int E) {
    __shared__ int h[NB];
    int j = blockIdx.x, t = threadIdx.x;
    for (int b = t; b < NB; b += SBLK) h[b] = 0;
    __syncthreads();
    int chunk = (E + PB - 1) / PB;
    int beg = j * chunk, end = min(beg + chunk, E);
    for (int e = beg + t; e < end; e += SBLK)
        atomicAdd(&h[((unsigned)dst[e]) >> BSH], 1);
    __syncthreads();
    for (int b = t; b < NB; b += SBLK) table[j * NB + b] = h[b];   // coalesced
}

__global__ void bucket_tot(const int* __restrict__ table, int* __restrict__ tot) {
    int b = blockIdx.x * blockDim.x + threadIdx.x;   // NB threads
    int s = 0;
    for (int j = 0; j < PB; ++j) s += table[j * NB + b];  // coalesced rows
    tot[b] = s;
}

__global__ void scan_base(const int* __restrict__ tot, int* __restrict__ base) {
    __shared__ int sm[BLK];
    int t = threadIdx.x;
    int loc[NB / BLK]; int s = 0;
#pragma unroll
    for (int k = 0; k < NB / BLK; ++k) { loc[k] = tot[t * (NB / BLK) + k]; s += loc[k]; }
    sm[t] = s; __syncthreads();
    int v = s;
    for (int off = 1; off < BLK; off <<= 1) {
        int add = (t >= off) ? sm[t - off] : 0;
        __syncthreads(); sm[t] += add; __syncthreads();
    }
    int run = sm[t] - v;   // exclusive across threads
#pragma unroll
    for (int k = 0; k < NB / BLK; ++k) { base[t * (NB / BLK) + k] = run; run += loc[k]; }
    if (t == BLK - 1) base[NB] = run;   // == E
}

// in-place: table[j][b] := bucket_base[b] + sum_{j'<j} table[j'][b]
__global__ void scan_table(int* __restrict__ table, const int* __restrict__ base) {
    int b = blockIdx.x * blockDim.x + threadIdx.x;
    int run = base[b];
    for (int j = 0; j < PB; ++j) {       // coalesced read+write per j
        int v = table[j * NB + b];
        table[j * NB + b] = run;
        run += v;
    }
}

// R9: block-local counting sort; emit bucket runs with dense coalesced stores.
__global__ __launch_bounds__(SBLK)
void scatter(const int* __restrict__ src, const int* __restrict__ dst,
             const int* __restrict__ table, unsigned* __restrict__ epart, int E) {
    __shared__ unsigned buf[BUFCAP];     // 62 KB
    __shared__ int h[NB];                // per-subchunk counts
    __shared__ int cur[NB];              // scan / fill cursor
    __shared__ int rbase[NB];            // running global base per bucket
    int j = blockIdx.x, t = threadIdx.x;
    for (int b = t; b < NB; b += SBLK) rbase[b] = table[j * NB + b];
    int chunk = (E + PB - 1) / PB;
    int beg = j * chunk, end = min(beg + chunk, E);
    for (int s = beg; s < end; s += BUFCAP) {
        int se = min(s + BUFCAP, end);
        for (int b = t; b < NB; b += SBLK) h[b] = 0;
        __syncthreads();
        for (int e = s + t; e < se; e += SBLK)
            atomicAdd(&h[((unsigned)dst[e]) >> BSH], 1);
        __syncthreads();
        // inclusive scan of h into cur (NB entries, Hillis-Steele)
        if (t < NB) cur[t] = h[t];
        __syncthreads();
        for (int off = 1; off < NB; off <<= 1) {
            int add = 0;
            if (t < NB && t >= off) add = cur[t - off];
            __syncthreads();
            if (t < NB) cur[t] += add;
            __syncthreads();
        }
        if (t < NB) cur[t] -= h[t];      // exclusive start
        __syncthreads();
        // fill LDS buffer sorted by bucket
        for (int e = s + t; e < se; e += SBLK) {
            unsigned d = (unsigned)dst[e];
            int b = d >> BSH;
            int slot = atomicAdd(&cur[b], 1);
            buf[slot] = ((d & 1023u) << 19) | (unsigned)src[e];
        }
        __syncthreads();
        // copy out: wave w handles buckets w, w+16, ... (runs are contiguous)
        int w = t >> 6, lane = t & 63;
        for (int b = w; b < NB; b += (SBLK >> 6)) {
            int n = h[b];
            int lo = cur[b] - n;         // cur is back to inclusive after fill
            int gb = rbase[b];
            for (int k = lane; k < n; k += 64)
                epart[gb + k] = buf[lo + k];
        }
        __syncthreads();
        if (t < NB) rbase[t] += h[t];
        __syncthreads();
    }
}

// one-time: within each bucket, order edges by local dst node (CSR) and emit
// rowp[node]. 1024 nodes/bucket, one node per thread. Writes land in a
// 64KB block-local region (L2-merged).
__global__ __launch_bounds__(1024)
void csr_build(const unsigned* __restrict__ epart, const int* __restrict__ base,
               unsigned* __restrict__ epart2, int* __restrict__ rowp) {
    __shared__ int cnt[1024];
    __shared__ int sc[1024];
    __shared__ int cur[1024];
    int b = blockIdx.x, t = threadIdx.x;
    cnt[t] = 0;
    __syncthreads();
    int beg = base[b], end = base[b + 1];
    for (int e = beg + t; e < end; e += 1024)
        atomicAdd(&cnt[epart[e] >> 19], 1);
    __syncthreads();
    int v = cnt[t];
    sc[t] = v; __syncthreads();
    for (int off = 1; off < 1024; off <<= 1) {
        int add = (t >= off) ? sc[t - off] : 0;
        __syncthreads(); sc[t] += add; __syncthreads();
    }
    int start = beg + sc[t] - v;       // exclusive, global slot
    rowp[b * 1024 + t] = start;
    if (t == 1023) rowp[b * 1024 + 1024] = end;   // dup of next block's t=0 (same value)
    cur[t] = start;
    __syncthreads();
    for (int e = beg + t; e < end; e += 1024) {
        unsigned p = epart[e];
        int slot = atomicAdd(&cur[p >> 19], 1);
        epart2[slot] = p & 0x7FFFFu;   // just src (19 bits)
    }
}

// node init; in-degree free from rowp
__global__ void init_nodes(const int* __restrict__ rl, const int* __restrict__ rowp,
                           float* __restrict__ dinv, float2* __restrict__ v0,
                           const int* __restrict__ flag, int N) {
    int i = blockIdx.x * blockDim.x + threadIdx.x;
    if (i < N) {
        int v = (*flag) ? rl[i] : rl[2 * i];
        float d = (float)(rowp[i + 1] - rowp[i]) + 1.0f;   // + self-loop
        dinv[i] = 1.0f / d;
        float rs = rsqrtf(d);
        float2 u; u.x = rs * ((float)v * (1.0f / 20000.0f)); u.y = rs;
        v0[i] = u;
    }
}

__global__ void coeffs(const float* __restrict__ W1, const float* __restrict__ b1,
                       const float* __restrict__ W2, const float* __restrict__ b2,
                       const float* __restrict__ W3, const float* __restrict__ b3,
                       const float* __restrict__ W4, const float* __restrict__ b4,
                       float* __restrict__ c) {
    __shared__ float p3[16], q3[16], r3[16];
    int t = threadIdx.x;
    if (t == 0) {
        float p2[8], q2[8];
        for (int j = 0; j < 8; ++j) {
            float s1 = 0.f, s2 = 0.f;
            for (int k = 0; k < 4; ++k) {
                float w = W2[k * 8 + j];
                s1 += W1[k] * w;
                s2 += b1[k] * w;
            }
            p2[j] = s1; q2[j] = s2;
        }
        for (int m = 0; m < 16; ++m) {
            float s1 = 0.f, s2 = 0.f, s3 = 0.f;
            for (int j = 0; j < 8; ++j) {
                float w = W3[j * 16 + m];
                s1 += p2[j] * w; s2 += q2[j] * w;
                s3 += b2[j] * w;
            }
            p3[m] = s1; q3[m] = s2; r3[m] = s3;
        }
    }
    __syncthreads();
    if (t < 32) {
        float c4 = 0.f, c3 = 0.f, c2 = 0.f, c1 = 0.f;
        for (int k = 0; k < 16; ++k) {
            float w = W4[k * 32 + t];
            c4 += p3[k] * w; c3 += q3[k] * w; c2 += r3[k] * w;
            c1 += b3[k] * w;
        }
        c[t] = c4; c[32 + t] = c3; c[64 + t] = c2; c[96 + t] = c1;
    }
}

// one sweep: 8 lanes/node (R9), register accumulate, x2 paired loads in flight
__global__ void gather_csr(const unsigned* __restrict__ epart2, const int* __restrict__ rowp,
                           const float2* __restrict__ vin, float2* __restrict__ vout,
                           const float* __restrict__ dinv, float* __restrict__ zsave, int N) {
    int t = blockIdx.x * blockDim.x + threadIdx.x;
    int i = t >> 3, l = t & 7;
    if (i >= N) return;
    int beg = rowp[i], end = rowp[i + 1];
    float a = 0.f, b = 0.f;
    int j = beg + l;
    for (; j + 8 < end; j += 16) {         // two independent loads in flight
        int s0 = epart2[j];
        int s1 = epart2[j + 8];
        float2 u0 = vin[s0];
        float2 u1 = vin[s1];
        a += u0.x + u1.x; b += u0.y + u1.y;
    }
    if (j < end) {
        float2 u = vin[epart2[j]];
        a += u.x; b += u.y;
    }
    a += __shfl_xor(a, 1); b += __shfl_xor(b, 1);
    a += __shfl_xor(a, 2); b += __shfl_xor(b, 2);
    a += __shfl_xor(a, 4); b += __shfl_xor(b, 4);
    if (l == 0) {
        float2 self = vin[i];
        float di = dinv[i];
        float2 o; o.x = (a + self.x) * di; o.y = (b + self.y) * di;
        vout[i] = o;
        if (zsave) zsave[i] = o.y;
    }
}

__global__ void write_out(const float2* __restrict__ v0, const float* __restrict__ z1,
                          const float* __restrict__ z2, const float* __restrict__ z3,
                          const float* __restrict__ dinv, const float* __restrict__ c,
                          const float* __restrict__ b4,
                          float* __restrict__ out, int N) {
    int t = blockIdx.x * blockDim.x + threadIdx.x;
    int i = t >> 5, f = t & 31;
    if (i < N) {
        float sq = rsqrtf(dinv[i]);  // = sqrt(deg)
        float v = sq * (v0[i].x * c[f] + z3[i] * c[32 + f] + z2[i] * c[64 + f]
                        + z1[i] * c[96 + f])
                  + b4[f];
        out[(size_t)i * 32 + f] = v;
    }
}

extern "C" void kernel_launch(void* const* d_in, const int* in_sizes, int n_in,
                              void* d_out, int out_size, void* d_ws, size_t ws_size,
                              hipStream_t stream) {
    const int N = in_sizes[0];
    const int E = in_sizes[1] / 2;
    const int* rl  = (const int*)d_in[0];
    const int* src = (const int*)d_in[1];
    const int* dst = src + E;
    const float* W1 = (const float*)d_in[2];
    const float* b1 = (const float*)d_in[3];
    const float* W2 = (const float*)d_in[4];
    const float* b2 = (const float*)d_in[5];
    const float* W3 = (const float*)d_in[6];
    const float* b3 = (const float*)d_in[7];
    const float* W4 = (const float*)d_in[8];
    const float* b4 = (const float*)d_in[9];

    const int gbNode = (N + 1023) / 1024;     // buckets containing nodes (489)
    const int rowpN  = gbNode * 1024 + 1;     // rowp entries

    // workspace (~19.1 MB)
    float*  dinv = (float*)d_ws;              // N
    float2* v0   = (float2*)(dinv + N);       // 2N floats
    float2* v1   = v0 + N;                    // 2N floats
    float*  z1   = (float*)(v1 + N);          // N
    float*  z2   = z1 + N;                    // N
    float*  z3   = z2 + N;                    // N
    int*    table = (int*)(z3 + N);           // PB*NB ints (1 MB)
    int*    rowp  = table + PB * NB;          // rowpN ints (~2 MB)
    int*    btot  = rowp + rowpN + 3;         // NB
    int*    bbase = btot + NB;                // NB+1
    float*  c     = (float*)(bbase + NB + 1); // 128
    int*    flag  = (int*)(c + 128);          // 1

    // packed edge arrays live in d_out (scratch until write_out)
    unsigned* epart  = (unsigned*)d_out;      // E uint32 (first 32 MB)
    unsigned* epart2 = epart + E;             // E uint32 (second 32 MB)

    hipMemsetAsync(flag, 0, sizeof(int), stream);
    probe_i64<<<1, BLK, 0, stream>>>(rl, flag);

    // radix partition by dst bucket — zero global atomics
    bucket_count<<<PB, SBLK, 0, stream>>>(dst, table, E);
    bucket_tot<<<NB / BLK, BLK, 0, stream>>>(table, btot);
    scan_base<<<1, BLK, 0, stream>>>(btot, bbase);
    scan_table<<<NB / BLK, BLK, 0, stream>>>(table, bbase);
    scatter<<<PB, SBLK, 0, stream>>>(src, dst, table, epart, E);

    // within-bucket CSR
    csr_build<<<gbNode, 1024, 0, stream>>>(epart, bbase, epart2, rowp);

    init_nodes<<<(N + BLK - 1) / BLK, BLK, 0, stream>>>(rl, rowp, dinv, v0, flag, N);
    coeffs<<<1, 64, 0, stream>>>(W1, b1, W2, b2, W3, b3, W4, b4, c);

    // 4 propagation sweeps, ping-pong v0<->v1 (8 lanes/node)
    const int gbG = (8 * N + BLK - 1) / BLK;
    gather_csr<<<gbG, BLK, 0, stream>>>(epart2, rowp, v0, v1, dinv, z1, N);
    gather_csr<<<gbG, BLK, 0, stream>>>(epart2, rowp, v1, v0, dinv, z2, N);
    gather_csr<<<gbG, BLK, 0, stream>>>(epart2, rowp, v0, v1, dinv, z3, N);
    gather_csr<<<gbG, BLK, 0, stream>>>(epart2, rowp, v1, v0, dinv, (float*)nullptr, N);

    write_out<<<(N * 32 + BLK - 1) / BLK, BLK, 0, stream>>>(
        v0, z1, z2, z3, dinv, c, b4, (float*)d_out, N);
}

// Round 3
// 457.748 us; speedup vs baseline: 1.3597x; 1.1306x over previous
//
#include <hip/hip_runtime.h>
#include <hip/hip_bf16.h>

// GCN 4-layer, linear network => collapse to:
// out = A^4 x0 * c4 + A^3 1 * c3 + A^2 1 * c2 + A 1 * c1 + b4,
// A = D^-1/2 (Adj+I) D^-1/2. Propagate in scaled space u' = D^-1 (Adj+I) u,
// epilogue multiplies sqrt(deg). Channels (x-path, ones-path) packed float2.
// Dtypes (R1-R4 verified): read_length int32, edge_index int32, W/b fp32, out fp32.
//
// R10: csr_build gets the R9 treatment. R9 counters: csr_build = 80us,
// WRITE_SIZE 248MB vs 34MB logical (same 7x partial-line RMW amplification
// the old scatter had — per-node LDS-cursor scatter into a 64KB global
// region, frontier ~ L2 size, thrashed by the streaming epart re-read).
// Fix: scatter into an LDS buffer (18176 entries = +14 sigma over the
// 16384-mean bucket load), then emit [beg,end) with sequential coalesced
// stores — every line written once, dense. Global-scatter fallback if a
// bucket ever exceeds the buffer. LDS 79KB -> still 2 blocks/CU.

#define BLK  256
#define SBLK 1024         // scatter/count block
#define NB   512          // buckets
#define BSH  10           // bucket = dst >> 10  (1024 nodes / bucket)
#define PB   512          // partition blocks
#define BUFCAP 15872      // scatter LDS sort buffer (chunk = ceil(8M/512) = 15625)
#define BUF2 18176        // csr_build LDS buffer (bucket mean 16384, sd ~128)

// If rl were int64 (values in [0,20000)), every odd int32 word is 0.
__global__ void probe_i64(const int* __restrict__ rl32, int* __restrict__ flag) {
    int acc = 0;
    for (int k = threadIdx.x; k < 1024; k += blockDim.x)
        acc |= rl32[2 * k + 1];
    if (acc != 0) atomicOr(flag, 1);   // 1 => int32 layout
}

__global__ __launch_bounds__(SBLK)
void bucket_count(const int* __restrict__ dst, int* __restrict__ table, int E) {
    __shared__ int h[NB];
    int j = blockIdx.x, t = threadIdx.x;
    for (int b = t; b < NB; b += SBLK) h[b] = 0;
    __syncthreads();
    int chunk = (E + PB - 1) / PB;
    int beg = j * chunk, end = min(beg + chunk, E);
    for (int e = beg + t; e < end; e += SBLK)
        atomicAdd(&h[((unsigned)dst[e]) >> BSH], 1);
    __syncthreads();
    for (int b = t; b < NB; b += SBLK) table[j * NB + b] = h[b];   // coalesced
}

__global__ void bucket_tot(const int* __restrict__ table, int* __restrict__ tot) {
    int b = blockIdx.x * blockDim.x + threadIdx.x;   // NB threads
    int s = 0;
    for (int j = 0; j < PB; ++j) s += table[j * NB + b];  // coalesced rows
    tot[b] = s;
}

__global__ void scan_base(const int* __restrict__ tot, int* __restrict__ base) {
    __shared__ int sm[BLK];
    int t = threadIdx.x;
    int loc[NB / BLK]; int s = 0;
#pragma unroll
    for (int k = 0; k < NB / BLK; ++k) { loc[k] = tot[t * (NB / BLK) + k]; s += loc[k]; }
    sm[t] = s; __syncthreads();
    int v = s;
    for (int off = 1; off < BLK; off <<= 1) {
        int add = (t >= off) ? sm[t - off] : 0;
        __syncthreads(); sm[t] += add; __syncthreads();
    }
    int run = sm[t] - v;   // exclusive across threads
#pragma unroll
    for (int k = 0; k < NB / BLK; ++k) { base[t * (NB / BLK) + k] = run; run += loc[k]; }
    if (t == BLK - 1) base[NB] = run;   // == E
}

// in-place: table[j][b] := bucket_base[b] + sum_{j'<j} table[j'][b]
__global__ void scan_table(int* __restrict__ table, const int* __restrict__ base) {
    int b = blockIdx.x * blockDim.x + threadIdx.x;
    int run = base[b];
    for (int j = 0; j < PB; ++j) {       // coalesced read+write per j
        int v = table[j * NB + b];
        table[j * NB + b] = run;
        run += v;
    }
}

// R9: block-local counting sort; emit bucket runs with dense coalesced stores.
__global__ __launch_bounds__(SBLK)
void scatter(const int* __restrict__ src, const int* __restrict__ dst,
             const int* __restrict__ table, unsigned* __restrict__ epart, int E) {
    __shared__ unsigned buf[BUFCAP];     // 62 KB
    __shared__ int h[NB];                // per-subchunk counts
    __shared__ int cur[NB];              // scan / fill cursor
    __shared__ int rbase[NB];            // running global base per bucket
    int j = blockIdx.x, t = threadIdx.x;
    for (int b = t; b < NB; b += SBLK) rbase[b] = table[j * NB + b];
    int chunk = (E + PB - 1) / PB;
    int beg = j * chunk, end = min(beg + chunk, E);
    for (int s = beg; s < end; s += BUFCAP) {
        int se = min(s + BUFCAP, end);
        for (int b = t; b < NB; b += SBLK) h[b] = 0;
        __syncthreads();
        for (int e = s + t; e < se; e += SBLK)
            atomicAdd(&h[((unsigned)dst[e]) >> BSH], 1);
        __syncthreads();
        // inclusive scan of h into cur (NB entries, Hillis-Steele)
        if (t < NB) cur[t] = h[t];
        __syncthreads();
        for (int off = 1; off < NB; off <<= 1) {
            int add = 0;
            if (t < NB && t >= off) add = cur[t - off];
            __syncthreads();
            if (t < NB) cur[t] += add;
            __syncthreads();
        }
        if (t < NB) cur[t] -= h[t];      // exclusive start
        __syncthreads();
        // fill LDS buffer sorted by bucket
        for (int e = s + t; e < se; e += SBLK) {
            unsigned d = (unsigned)dst[e];
            int b = d >> BSH;
            int slot = atomicAdd(&cur[b], 1);
            buf[slot] = ((d & 1023u) << 19) | (unsigned)src[e];
        }
        __syncthreads();
        // copy out: wave w handles buckets w, w+16, ... (runs are contiguous)
        int w = t >> 6, lane = t & 63;
        for (int b = w; b < NB; b += (SBLK >> 6)) {
            int n = h[b];
            int lo = cur[b] - n;         // cur is back to inclusive after fill
            int gb = rbase[b];
            for (int k = lane; k < n; k += 64)
                epart[gb + k] = buf[lo + k];
        }
        __syncthreads();
        if (t < NB) rbase[t] += h[t];
        __syncthreads();
    }
}

// one-time: within each bucket, order edges by local dst node (CSR) and emit
// rowp[node]. 1024 nodes/bucket, one node per thread. R10: scatter lands in
// LDS, then one dense coalesced sweep to global (kills write amplification).
__global__ __launch_bounds__(1024)
void csr_build(const unsigned* __restrict__ epart, const int* __restrict__ base,
               unsigned* __restrict__ epart2, int* __restrict__ rowp) {
    __shared__ unsigned buf[BUF2];     // 71 KB
    __shared__ int sc[1024];           // counts -> inclusive scan (in place)
    __shared__ int cur[1024];          // fill cursors (local slots)
    int b = blockIdx.x, t = threadIdx.x;
    int beg = base[b], end = base[b + 1];
    int n = end - beg;
    sc[t] = 0;
    __syncthreads();
    for (int e = beg + t; e < end; e += 1024)
        atomicAdd(&sc[epart[e] >> 19], 1);
    __syncthreads();
    int v = sc[t];
    for (int off = 1; off < 1024; off <<= 1) {
        int add = (t >= off) ? sc[t - off] : 0;
        __syncthreads(); sc[t] += add; __syncthreads();
    }
    int start = sc[t] - v;             // exclusive, bucket-local slot
    rowp[b * 1024 + t] = beg + start;
    if (t == 1023) rowp[b * 1024 + 1024] = end;   // dup of next block's t=0 (same value)
    cur[t] = start;
    __syncthreads();
    if (n <= BUF2) {
        // sort into LDS
        for (int e = beg + t; e < end; e += 1024) {
            unsigned p = epart[e];
            int slot = atomicAdd(&cur[p >> 19], 1);
            buf[slot] = p & 0x7FFFFu;   // just src (19 bits)
        }
        __syncthreads();
        // dense coalesced write-out: lines written once, full
        for (int k = t; k < n; k += 1024)
            epart2[beg + k] = buf[k];
    } else {
        // overflow fallback (statistically unreachable): global scatter
        for (int e = beg + t; e < end; e += 1024) {
            unsigned p = epart[e];
            int slot = atomicAdd(&cur[p >> 19], 1);
            epart2[beg + slot] = p & 0x7FFFFu;
        }
    }
}

// node init; in-degree free from rowp
__global__ void init_nodes(const int* __restrict__ rl, const int* __restrict__ rowp,
                           float* __restrict__ dinv, float2* __restrict__ v0,
                           const int* __restrict__ flag, int N) {
    int i = blockIdx.x * blockDim.x + threadIdx.x;
    if (i < N) {
        int v = (*flag) ? rl[i] : rl[2 * i];
        float d = (float)(rowp[i + 1] - rowp[i]) + 1.0f;   // + self-loop
        dinv[i] = 1.0f / d;
        float rs = rsqrtf(d);
        float2 u; u.x = rs * ((float)v * (1.0f / 20000.0f)); u.y = rs;
        v0[i] = u;
    }
}

__global__ void coeffs(const float* __restrict__ W1, const float* __restrict__ b1,
                       const float* __restrict__ W2, const float* __restrict__ b2,
                       const float* __restrict__ W3, const float* __restrict__ b3,
                       const float* __restrict__ W4, const float* __restrict__ b4,
                       float* __restrict__ c) {
    __shared__ float p3[16], q3[16], r3[16];
    int t = threadIdx.x;
    if (t == 0) {
        float p2[8], q2[8];
        for (int j = 0; j < 8; ++j) {
            float s1 = 0.f, s2 = 0.f;
            for (int k = 0; k < 4; ++k) {
                float w = W2[k * 8 + j];
                s1 += W1[k] * w;
                s2 += b1[k] * w;
            }
            p2[j] = s1; q2[j] = s2;
        }
        for (int m = 0; m < 16; ++m) {
            float s1 = 0.f, s2 = 0.f, s3 = 0.f;
            for (int j = 0; j < 8; ++j) {
                float w = W3[j * 16 + m];
                s1 += p2[j] * w; s2 += q2[j] * w;
                s3 += b2[j] * w;
            }
            p3[m] = s1; q3[m] = s2; r3[m] = s3;
        }
    }
    __syncthreads();
    if (t < 32) {
        float c4 = 0.f, c3 = 0.f, c2 = 0.f, c1 = 0.f;
        for (int k = 0; k < 16; ++k) {
            float w = W4[k * 32 + t];
            c4 += p3[k] * w; c3 += q3[k] * w; c2 += r3[k] * w;
            c1 += b3[k] * w;
        }
        c[t] = c4; c[32 + t] = c3; c[64 + t] = c2; c[96 + t] = c1;
    }
}

// one sweep: 8 lanes/node, register accumulate, x2 paired loads in flight
__global__ void gather_csr(const unsigned* __restrict__ epart2, const int* __restrict__ rowp,
                           const float2* __restrict__ vin, float2* __restrict__ vout,
                           const float* __restrict__ dinv, float* __restrict__ zsave, int N) {
    int t = blockIdx.x * blockDim.x + threadIdx.x;
    int i = t >> 3, l = t & 7;
    if (i >= N) return;
    int beg = rowp[i], end = rowp[i + 1];
    float a = 0.f, b = 0.f;
    int j = beg + l;
    for (; j + 8 < end; j += 16) {         // two independent loads in flight
        int s0 = epart2[j];
        int s1 = epart2[j + 8];
        float2 u0 = vin[s0];
        float2 u1 = vin[s1];
        a += u0.x + u1.x; b += u0.y + u1.y;
    }
    if (j < end) {
        float2 u = vin[epart2[j]];
        a += u.x; b += u.y;
    }
    a += __shfl_xor(a, 1); b += __shfl_xor(b, 1);
    a += __shfl_xor(a, 2); b += __shfl_xor(b, 2);
    a += __shfl_xor(a, 4); b += __shfl_xor(b, 4);
    if (l == 0) {
        float2 self = vin[i];
        float di = dinv[i];
        float2 o; o.x = (a + self.x) * di; o.y = (b + self.y) * di;
        vout[i] = o;
        if (zsave) zsave[i] = o.y;
    }
}

__global__ void write_out(const float2* __restrict__ v0, const float* __restrict__ z1,
                          const float* __restrict__ z2, const float* __restrict__ z3,
                          const float* __restrict__ dinv, const float* __restrict__ c,
                          const float* __restrict__ b4,
                          float* __restrict__ out, int N) {
    int t = blockIdx.x * blockDim.x + threadIdx.x;
    int i = t >> 5, f = t & 31;
    if (i < N) {
        float sq = rsqrtf(dinv[i]);  // = sqrt(deg)
        float v = sq * (v0[i].x * c[f] + z3[i] * c[32 + f] + z2[i] * c[64 + f]
                        + z1[i] * c[96 + f])
                  + b4[f];
        out[(size_t)i * 32 + f] = v;
    }
}

extern "C" void kernel_launch(void* const* d_in, const int* in_sizes, int n_in,
                              void* d_out, int out_size, void* d_ws, size_t ws_size,
                              hipStream_t stream) {
    const int N = in_sizes[0];
    const int E = in_sizes[1] / 2;
    const int* rl  = (const int*)d_in[0];
    const int* src = (const int*)d_in[1];
    const int* dst = src + E;
    const float* W1 = (const float*)d_in[2];
    const float* b1 = (const float*)d_in[3];
    const float* W2 = (const float*)d_in[4];
    const float* b2 = (const float*)d_in[5];
    const float* W3 = (const float*)d_in[6];
    const float* b3 = (const float*)d_in[7];
    const float* W4 = (const float*)d_in[8];
    const float* b4 = (const float*)d_in[9];

    const int gbNode = (N + 1023) / 1024;     // buckets containing nodes (489)
    const int rowpN  = gbNode * 1024 + 1;     // rowp entries

    // workspace (~19.1 MB)
    float*  dinv = (float*)d_ws;              // N
    float2* v0   = (float2*)(dinv + N);       // 2N floats
    float2* v1   = v0 + N;                    // 2N floats
    float*  z1   = (float*)(v1 + N);          // N
    float*  z2   = z1 + N;                    // N
    float*  z3   = z2 + N;                    // N
    int*    table = (int*)(z3 + N);           // PB*NB ints (1 MB)
    int*    rowp  = table + PB * NB;          // rowpN ints (~2 MB)
    int*    btot  = rowp + rowpN + 3;         // NB
    int*    bbase = btot + NB;                // NB+1
    float*  c     = (float*)(bbase + NB + 1); // 128
    int*    flag  = (int*)(c + 128);          // 1

    // packed edge arrays live in d_out (scratch until write_out)
    unsigned* epart  = (unsigned*)d_out;      // E uint32 (first 32 MB)
    unsigned* epart2 = epart + E;             // E uint32 (second 32 MB)

    hipMemsetAsync(flag, 0, sizeof(int), stream);
    probe_i64<<<1, BLK, 0, stream>>>(rl, flag);

    // radix partition by dst bucket — zero global atomics
    bucket_count<<<PB, SBLK, 0, stream>>>(dst, table, E);
    bucket_tot<<<NB / BLK, BLK, 0, stream>>>(table, btot);
    scan_base<<<1, BLK, 0, stream>>>(btot, bbase);
    scan_table<<<NB / BLK, BLK, 0, stream>>>(table, bbase);
    scatter<<<PB, SBLK, 0, stream>>>(src, dst, table, epart, E);

    // within-bucket CSR
    csr_build<<<gbNode, 1024, 0, stream>>>(epart, bbase, epart2, rowp);

    init_nodes<<<(N + BLK - 1) / BLK, BLK, 0, stream>>>(rl, rowp, dinv, v0, flag, N);
    coeffs<<<1, 64, 0, stream>>>(W1, b1, W2, b2, W3, b3, W4, b4, c);

    // 4 propagation sweeps, ping-pong v0<->v1 (8 lanes/node)
    const int gbG = (8 * N + BLK - 1) / BLK;
    gather_csr<<<gbG, BLK, 0, stream>>>(epart2, rowp, v0, v1, dinv, z1, N);
    gather_csr<<<gbG, BLK, 0, stream>>>(epart2, rowp, v1, v0, dinv, z2, N);
    gather_csr<<<gbG, BLK, 0, stream>>>(epart2, rowp, v0, v1, dinv, z3, N);
    gather_csr<<<gbG, BLK, 0, stream>>>(epart2, rowp, v1, v0, dinv, (float*)nullptr, N);

    write_out<<<(N * 32 + BLK - 1) / BLK, BLK, 0, stream>>>(
        v0, z1, z2, z3, dinv, c, b4, (float*)d_out, N);
}